// Round 3
// baseline (3643.555 us; speedup 1.0000x reference)
//
#include <hip/hip_runtime.h>
#include <hip/hip_bf16.h>

#define B 16
#define P 1024
#define NPT 16384   // B*P
#define KNN 16
#define MID 96
#define HD 64

// ws layout (in floats)
#define WS_UV   0                        // NPT*192
#define WS_RN   (WS_UV + NPT*192)        // NPT
#define WS_NBR  (WS_RN + NPT)            // NPT*KNN ints
#define WS_WUV  (WS_NBR + NPT*KNN)       // up to 192*192
#define WS_CVEC (WS_WUV + 192*192)       // 96
#define WS_PART (WS_CVEC + 96)           // B*16*256

// ---------------- input MLP: 5 -> 128 -> 128 -> 64, writes cols 192..255 ----
__global__ void k_input(const float* __restrict__ x, const float* __restrict__ dn,
                        const float* __restrict__ w1, const float* __restrict__ b1,
                        const float* __restrict__ w2, const float* __restrict__ b2,
                        const float* __restrict__ w3, const float* __restrict__ b3,
                        float* __restrict__ Hout) {
    __shared__ float xs[8][5];
    __shared__ float t1[8][128];
    __shared__ float t2[8][128];
    int tid = threadIdx.x;            // 128 threads
    int p0 = blockIdx.x * 8;
    if (tid < 40) { int p = tid / 5, f = tid - p * 5; xs[p][f] = x[(p0 + p) * 5 + f] * dn[f]; }
    __syncthreads();
    int c = tid;
    {
        float bb = b1[c];
        #pragma unroll
        for (int p = 0; p < 8; p++) {
            float a = bb;
            #pragma unroll
            for (int f = 0; f < 5; f++) a += xs[p][f] * w1[f * 128 + c];
            t1[p][c] = fmaxf(a, 0.f);
        }
    }
    __syncthreads();
    {
        float acc[8];
        float bb = b2[c];
        #pragma unroll
        for (int p = 0; p < 8; p++) acc[p] = bb;
        for (int k = 0; k < 128; k++) {
            float w = w2[k * 128 + c];
            #pragma unroll
            for (int p = 0; p < 8; p++) acc[p] += t1[p][k] * w;
        }
        #pragma unroll
        for (int p = 0; p < 8; p++) t2[p][c] = fmaxf(acc[p], 0.f);
    }
    __syncthreads();
    if (c < 64) {
        float acc[8];
        float bb = b3[c];
        #pragma unroll
        for (int p = 0; p < 8; p++) acc[p] = bb;
        for (int k = 0; k < 128; k++) {
            float w = w3[k * 64 + c];
            #pragma unroll
            for (int p = 0; p < 8; p++) acc[p] += t2[p][k] * w;
        }
        #pragma unroll
        for (int p = 0; p < 8; p++) Hout[(p0 + p) * 256 + 192 + c] = fmaxf(acc[p], 0.f);
    }
}

// ---------------- per-conv weight prep: WUV = [(top-bot)*s | bot*s], cvec ----
__global__ void k_prep(const float* __restrict__ wa, const float* __restrict__ ba,
                       const float* __restrict__ g, const float* __restrict__ bB,
                       const float* __restrict__ m, const float* __restrict__ v,
                       int D, float* __restrict__ WUV, float* __restrict__ cvec) {
    int idx = blockIdx.x * 256 + threadIdx.x;
    if (idx < D * 192) {
        int k = idx / 192, col = idx - k * 192;
        int ch = (col < 96) ? col : col - 96;
        float s = g[ch] * rsqrtf(v[ch] + 1e-5f);
        float w = (col < 96) ? (wa[k * 96 + ch] - wa[(D + k) * 96 + ch]) : wa[(D + k) * 96 + ch];
        WUV[idx] = w * s;
    }
    if (blockIdx.x == 0 && threadIdx.x < 96) {
        int ch = threadIdx.x;
        float s = g[ch] * rsqrtf(v[ch] + 1e-5f);
        cvec[ch] = ba[ch] * s + (bB[ch] - m[ch] * s);
    }
}

// ---------------- row inverse norms ----------------
__global__ void k_rn(const float* __restrict__ Hout, int colOff, int D, float* __restrict__ rn) {
    int p = blockIdx.x * 256 + threadIdx.x;
    if (p >= NPT) return;
    const float* r = Hout + p * 256 + colOff;
    float ss = 0.f;
    for (int d = 0; d < D; d++) { float v = r[d]; ss += v * v; }
    rn[p] = rsqrtf(ss + 1e-12f);
}

// ---------------- fused cosine-sim + ballot-filter blind-insert top-16 ------
#define XI_LD 196

__device__ __forceinline__ unsigned long long packkey(float v, int q) {
    unsigned u = __float_as_uint(v);
    u = (u & 0x80000000u) ? ~u : (u | 0x80000000u);
    return ((unsigned long long)u << 32) | (unsigned)(1023 - q);
}

__global__ void __launch_bounds__(256) k_knn(const float* __restrict__ Hout, int colOff, int D,
                                             const float* __restrict__ rn, int* __restrict__ nbr) {
    __shared__ __align__(16) float Xi[16 * XI_LD];
    int tid = threadIdx.x;
    int b = blockIdx.x >> 6;
    int i0 = (blockIdx.x & 63) * 16;
    for (int idx = tid; idx < 16 * D; idx += 256) {
        int r = idx / D, d = idx - r * D;
        Xi[r * XI_LD + d] = Hout[(size_t)(b * P + i0 + r) * 256 + colOff + d];
    }
    int lane = tid & 63, w = tid >> 6;
    int g = lane >> 4, lane16 = lane & 15;
    int row = w * 4 + g;                   // row this thread computes AND merges
    int sh = lane & 48;
    int ig = i0 + row;
    float rni = rn[b * P + ig];
    const float4* xi4 = (const float4*)(Xi + row * XI_LD);
    int nd4 = D >> 2;
    unsigned long long listkey = 0ull;     // lane16-th entry of row's sorted top-16
    __syncthreads();
    for (int qt = 0; qt < 16; qt++) {
        int qa = qt * 64 + lane16;         // candidate q for slot s is qa + 16*s
        const float4* pq = (const float4*)(Hout + (size_t)(b * P + qa) * 256 + colOff);
        float a0 = 0.f, a1 = 0.f, a2 = 0.f, a3 = 0.f;
        for (int d4 = 0; d4 < nd4; d4++) {
            float4 xv = xi4[d4];
            float4 p0 = pq[d4];
            float4 p1 = pq[d4 + 1024];
            float4 p2 = pq[d4 + 2048];
            float4 p3 = pq[d4 + 3072];
            a0 += xv.x * p0.x; a0 += xv.y * p0.y; a0 += xv.z * p0.z; a0 += xv.w * p0.w;
            a1 += xv.x * p1.x; a1 += xv.y * p1.y; a1 += xv.z * p1.z; a1 += xv.w * p1.w;
            a2 += xv.x * p2.x; a2 += xv.y * p2.y; a2 += xv.z * p2.z; a2 += xv.w * p2.w;
            a3 += xv.x * p3.x; a3 += xv.y * p3.y; a3 += xv.z * p3.z; a3 += xv.w * p3.w;
        }
        float v0 = a0 * rni * rn[b * P + qa];
        float v1 = a1 * rni * rn[b * P + qa + 16];
        float v2 = a2 * rni * rn[b * P + qa + 32];
        float v3 = a3 * rni * rn[b * P + qa + 48];
        if (qa      == ig) v0 = -1e9f;
        if (qa + 16 == ig) v1 = -1e9f;
        if (qa + 32 == ig) v2 = -1e9f;
        if (qa + 48 == ig) v3 = -1e9f;
        unsigned long long c0 = packkey(v0, qa);
        unsigned long long c1 = packkey(v1, qa + 16);
        unsigned long long c2 = packkey(v2, qa + 32);
        unsigned long long c3 = packkey(v3, qa + 48);
        unsigned long long lmin = __shfl(listkey, 15, 16);
        unsigned long long b0 = __ballot(c0 > lmin);
        unsigned long long b1 = __ballot(c1 > lmin);
        unsigned long long b2 = __ballot(c2 > lmin);
        unsigned long long b3 = __ballot(c3 > lmin);
        unsigned long long gm = ((b0 >> sh) & 0xFFFFull)
                              | (((b1 >> sh) & 0xFFFFull) << 16)
                              | (((b2 >> sh) & 0xFFFFull) << 32)
                              | (((b3 >> sh) & 0xFFFFull) << 48);
        // blind insert: stale (too-small) candidates self-discard (pos==16 -> no-op)
        while (gm) {
            int pb = __builtin_ctzll(gm);
            gm &= gm - 1;
            int slot = pb >> 4, src = pb & 15;
            unsigned long long sel = (slot & 2) ? ((slot & 1) ? c3 : c2)
                                                : ((slot & 1) ? c1 : c0);
            unsigned long long mv = __shfl(sel, src, 16);
            unsigned long long bal = __ballot(listkey > mv);
            int pos = __popcll((bal >> sh) & 0xFFFFull);
            unsigned long long up = __shfl_up(listkey, 1, 16);
            if (lane16 == pos) listkey = mv;
            else if (lane16 > pos) listkey = up;
        }
    }
    nbr[((size_t)b * P + i0 + row) * KNN + lane16] = 1023 - (int)(listkey & 0xFFFFFFFFull);
}

// ---------------- UV projection: [16384, D] @ [D, 192] ----------------
__global__ void k_uv(const float* __restrict__ Hout, int colOff, int D,
                     const float* __restrict__ WUV, float* __restrict__ UV) {
    __shared__ float Xt[16 * 192];
    int tid = threadIdx.x;   // 192 threads
    int p0 = blockIdx.x * 16;
    for (int idx = tid; idx < 16 * D; idx += 192) {
        int r = idx / D, d = idx - r * D;
        Xt[r * 192 + d] = Hout[(p0 + r) * 256 + colOff + d];
    }
    __syncthreads();
    float acc[16];
    #pragma unroll
    for (int p = 0; p < 16; p++) acc[p] = 0.f;
    for (int k = 0; k < D; k++) {
        float w = WUV[k * 192 + tid];
        #pragma unroll
        for (int p = 0; p < 16; p++) acc[p] += Xt[p * 192 + k] * w;
    }
    #pragma unroll
    for (int p = 0; p < 16; p++) UV[(size_t)(p0 + p) * 192 + tid] = acc[p];
}

// ---------------- per-edge message kernel (wb in VGPRs, no inner barriers) --
__global__ void __launch_bounds__(256) k_edge(const float* __restrict__ UV, const int* __restrict__ nbr,
                                              const float* __restrict__ wb, const float* __restrict__ bbv,
                                              const float* __restrict__ cvec, int colOut,
                                              float* __restrict__ Hout) {
    __shared__ __align__(16) float m1s[4][96];   // wave-private message buffer
    __shared__ float cvs[96];
    __shared__ float bbs[64];
    int tid = threadIdx.x;
    int w = tid >> 6, lane = tid & 63;
    float wreg[96];                              // wb column `lane` in registers
    #pragma unroll
    for (int k = 0; k < 96; k++) wreg[k] = wb[k * 64 + lane];
    if (tid < 96) cvs[tid] = cvec[tid];
    if (tid < 64) bbs[tid] = bbv[tid];
    int ifl = blockIdx.x * 4 + w;
    int b = ifl >> 10, i = ifl & 1023;
    const float* Ui = UV + (size_t)ifl * 192;
    float ui0 = Ui[lane];
    float ui1 = (lane < 32) ? Ui[64 + lane] : 0.f;
    float vi0 = Ui[96 + lane];
    float vi1 = (lane < 32) ? Ui[160 + lane] : 0.f;
    float accA = 0.f;
    __syncthreads();
    float bbl = bbs[lane];
    float cv0 = cvs[lane];
    float cv1 = (lane < 32) ? cvs[64 + lane] : 0.f;
    const float4* m4 = (const float4*)m1s[w];
    for (int kk = 0; kk < KNN; kk++) {
        int j = nbr[ifl * KNN + kk];
        int jf = b * P + j;
        bool mut = __any((lane < KNN) ? (nbr[jf * KNN + lane] == i) : 0);
        const float* Uj = UV + (size_t)jf * 192;
        // forward message: center i, neighbor j   (wave-private -> no barrier)
        m1s[w][lane] = fmaxf(ui0 + Uj[96 + lane] + cv0, 0.f);
        if (lane < 32) m1s[w][64 + lane] = fmaxf(ui1 + Uj[160 + lane] + cv1, 0.f);
        float t = bbl;
        #pragma unroll
        for (int k4 = 0; k4 < 24; k4++) {
            float4 mv = m4[k4];
            t += mv.x * wreg[k4 * 4 + 0];
            t += mv.y * wreg[k4 * 4 + 1];
            t += mv.z * wreg[k4 * 4 + 2];
            t += mv.w * wreg[k4 * 4 + 3];
        }
        accA += fmaxf(t, 0.f);
        // reverse message: center j, neighbor i
        m1s[w][lane] = fmaxf(Uj[lane] + vi0 + cv0, 0.f);
        if (lane < 32) m1s[w][64 + lane] = fmaxf(Uj[64 + lane] + vi1 + cv1, 0.f);
        float t2 = bbl;
        #pragma unroll
        for (int k4 = 0; k4 < 24; k4++) {
            float4 mv = m4[k4];
            t2 += mv.x * wreg[k4 * 4 + 0];
            t2 += mv.y * wreg[k4 * 4 + 1];
            t2 += mv.z * wreg[k4 * 4 + 2];
            t2 += mv.w * wreg[k4 * 4 + 3];
        }
        if (!mut) atomicAdd(&Hout[(size_t)jf * 256 + colOut + lane], fmaxf(t2, 0.f));
    }
    atomicAdd(&Hout[(size_t)ifl * 256 + colOut + lane], accA);
}

// ---------------- global max pool (partial) ----------------
__global__ void k_pool(const float* __restrict__ Hout, float* __restrict__ part) {
    int tid = threadIdx.x;
    int b = blockIdx.x >> 4, pt = blockIdx.x & 15;
    float mv = -1e30f;
    for (int p = pt * 64; p < pt * 64 + 64; p++)
        mv = fmaxf(mv, Hout[(size_t)(b * P + p) * 256 + tid]);
    part[(b * 16 + pt) * 256 + tid] = mv;
}

// ---------------- final reduce + output MLP ----------------
__global__ void k_out(const float* __restrict__ part,
                      const float* __restrict__ w1, const float* __restrict__ b1,
                      const float* __restrict__ w2, const float* __restrict__ b2,
                      const float* __restrict__ w3, const float* __restrict__ b3,
                      float* __restrict__ out) {
    __shared__ float pooled[256];
    __shared__ float r1[128];
    __shared__ float r2[32];
    int tid = threadIdx.x, b = blockIdx.x;
    float mv = -1e30f;
    for (int t = 0; t < 16; t++) mv = fmaxf(mv, part[(b * 16 + t) * 256 + tid]);
    pooled[tid] = mv;
    __syncthreads();
    if (tid < 128) {
        float a = b1[tid];
        for (int k = 0; k < 256; k++) a += pooled[k] * w1[k * 128 + tid];
        r1[tid] = fmaxf(a, 0.f);
    }
    __syncthreads();
    if (tid < 32) {
        float a = b2[tid];
        for (int k = 0; k < 128; k++) a += r1[k] * w2[k * 32 + tid];
        r2[tid] = fmaxf(a, 0.f);
    }
    __syncthreads();
    if (tid == 0) {
        float a = b3[0];
        for (int k = 0; k < 32; k++) a += r2[k] * w3[k];
        out[b] = a;
    }
}

extern "C" void kernel_launch(void* const* d_in, const int* in_sizes, int n_in,
                              void* d_out, int out_size, void* d_ws, size_t ws_size,
                              hipStream_t stream) {
    const float* x  = (const float*)d_in[0];
    const float* dn = (const float*)d_in[1];
    float* out = (float*)d_out;
    float* Hout = out + 16;           // [16384][256] feature/output buffer
    float* ws = (float*)d_ws;
    float* UV   = ws + WS_UV;
    float* rn   = ws + WS_RN;
    int*   nbr  = (int*)(ws + WS_NBR);
    float* WUV  = ws + WS_WUV;
    float* cvec = ws + WS_CVEC;
    float* part = ws + WS_PART;

    hipMemsetAsync(d_out, 0, (size_t)out_size * sizeof(float), stream);

    k_input<<<2048, 128, 0, stream>>>(x, dn,
        (const float*)d_in[2], (const float*)d_in[3],
        (const float*)d_in[4], (const float*)d_in[5],
        (const float*)d_in[6], (const float*)d_in[7], Hout);

    const int convOff[3] = {192, 128, 64};   // input column offset
    const int convD[3]   = {64, 128, 192};   // input feature width
    const int convOut[3] = {128, 64, 0};     // output column offset
    for (int c = 0; c < 3; c++) {
        int pb = 8 + c * 8;
        const float* wa  = (const float*)d_in[pb + 0];
        const float* ba  = (const float*)d_in[pb + 1];
        const float* g   = (const float*)d_in[pb + 2];
        const float* bB  = (const float*)d_in[pb + 3];
        const float* m   = (const float*)d_in[pb + 4];
        const float* v   = (const float*)d_in[pb + 5];
        const float* wb  = (const float*)d_in[pb + 6];
        const float* bbv = (const float*)d_in[pb + 7];
        int D = convD[c], off = convOff[c], co = convOut[c];
        k_prep<<<(D * 192 + 255) / 256, 256, 0, stream>>>(wa, ba, g, bB, m, v, D, WUV, cvec);
        k_rn<<<64, 256, 0, stream>>>(Hout, off, D, rn);
        k_knn<<<1024, 256, 0, stream>>>(Hout, off, D, rn, nbr);
        k_uv<<<1024, 192, 0, stream>>>(Hout, off, D, WUV, UV);
        k_edge<<<4096, 256, 0, stream>>>(UV, nbr, wb, bbv, cvec, co, Hout);
    }

    k_pool<<<256, 256, 0, stream>>>(Hout, part);
    k_out<<<16, 256, 0, stream>>>(part,
        (const float*)d_in[32], (const float*)d_in[33],
        (const float*)d_in[34], (const float*)d_in[35],
        (const float*)d_in[36], (const float*)d_in[37], out);
}

// Round 4
// 1722.154 us; speedup vs baseline: 2.1157x; 2.1157x over previous
//
#include <hip/hip_runtime.h>
#include <hip/hip_bf16.h>

#define B 16
#define P 1024
#define NPT 16384   // B*P
#define KNN 16
#define MID 96
#define HD 64

// ws layout (in floats)
#define WS_UV   0                        // NPT*192
#define WS_RN   (WS_UV + NPT*192)        // NPT
#define WS_NBR  (WS_RN + NPT)            // NPT*KNN ints
#define WS_WUV  (WS_NBR + NPT*KNN)       // up to 192*192
#define WS_CVEC (WS_WUV + 192*192)       // 96
#define WS_PART (WS_CVEC + 96)           // B*16*256

// ---------------- input MLP: 5 -> 128 -> 128 -> 64, writes cols 192..255 ----
__global__ void k_input(const float* __restrict__ x, const float* __restrict__ dn,
                        const float* __restrict__ w1, const float* __restrict__ b1,
                        const float* __restrict__ w2, const float* __restrict__ b2,
                        const float* __restrict__ w3, const float* __restrict__ b3,
                        float* __restrict__ Hout) {
    __shared__ float xs[8][5];
    __shared__ float t1[8][128];
    __shared__ float t2[8][128];
    int tid = threadIdx.x;            // 128 threads
    int p0 = blockIdx.x * 8;
    if (tid < 40) { int p = tid / 5, f = tid - p * 5; xs[p][f] = x[(p0 + p) * 5 + f] * dn[f]; }
    __syncthreads();
    int c = tid;
    {
        float bb = b1[c];
        #pragma unroll
        for (int p = 0; p < 8; p++) {
            float a = bb;
            #pragma unroll
            for (int f = 0; f < 5; f++) a += xs[p][f] * w1[f * 128 + c];
            t1[p][c] = fmaxf(a, 0.f);
        }
    }
    __syncthreads();
    {
        float acc[8];
        float bb = b2[c];
        #pragma unroll
        for (int p = 0; p < 8; p++) acc[p] = bb;
        for (int k = 0; k < 128; k++) {
            float w = w2[k * 128 + c];
            #pragma unroll
            for (int p = 0; p < 8; p++) acc[p] += t1[p][k] * w;
        }
        #pragma unroll
        for (int p = 0; p < 8; p++) t2[p][c] = fmaxf(acc[p], 0.f);
    }
    __syncthreads();
    if (c < 64) {
        float acc[8];
        float bb = b3[c];
        #pragma unroll
        for (int p = 0; p < 8; p++) acc[p] = bb;
        for (int k = 0; k < 128; k++) {
            float w = w3[k * 64 + c];
            #pragma unroll
            for (int p = 0; p < 8; p++) acc[p] += t2[p][k] * w;
        }
        #pragma unroll
        for (int p = 0; p < 8; p++) Hout[(p0 + p) * 256 + 192 + c] = fmaxf(acc[p], 0.f);
    }
}

// ---------------- per-conv weight prep: WUV = [(top-bot)*s | bot*s], cvec ----
__global__ void k_prep(const float* __restrict__ wa, const float* __restrict__ ba,
                       const float* __restrict__ g, const float* __restrict__ bB,
                       const float* __restrict__ m, const float* __restrict__ v,
                       int D, float* __restrict__ WUV, float* __restrict__ cvec) {
    int idx = blockIdx.x * 256 + threadIdx.x;
    if (idx < D * 192) {
        int k = idx / 192, col = idx - k * 192;
        int ch = (col < 96) ? col : col - 96;
        float s = g[ch] * rsqrtf(v[ch] + 1e-5f);
        float w = (col < 96) ? (wa[k * 96 + ch] - wa[(D + k) * 96 + ch]) : wa[(D + k) * 96 + ch];
        WUV[idx] = w * s;
    }
    if (blockIdx.x == 0 && threadIdx.x < 96) {
        int ch = threadIdx.x;
        float s = g[ch] * rsqrtf(v[ch] + 1e-5f);
        cvec[ch] = ba[ch] * s + (bB[ch] - m[ch] * s);
    }
}

// ---------------- row inverse norms ----------------
__global__ void k_rn(const float* __restrict__ Hout, int colOff, int D, float* __restrict__ rn) {
    int p = blockIdx.x * 256 + threadIdx.x;
    if (p >= NPT) return;
    const float* r = Hout + p * 256 + colOff;
    float ss = 0.f;
    for (int d = 0; d < D; d++) { float v = r[d]; ss += v * v; }
    rn[p] = rsqrtf(ss + 1e-12f);
}

// ------ fused cosine-sim (R2 coalesced mapping) + ballot blind-insert top-16
#define XI_LD 196
#define ST_LD 69

__device__ __forceinline__ unsigned long long packkey(float v, int q) {
    unsigned u = __float_as_uint(v);
    u = (u & 0x80000000u) ? ~u : (u | 0x80000000u);
    return ((unsigned long long)u << 32) | (unsigned)(1023 - q);
}

__global__ void __launch_bounds__(256) k_knn(const float* __restrict__ Hout, int colOff, int D,
                                             const float* __restrict__ rn, int* __restrict__ nbr) {
    __shared__ __align__(16) float Xi[16 * XI_LD];
    __shared__ float simtile[16 * ST_LD];
    int tid = threadIdx.x;
    int b = blockIdx.x >> 6;
    int i0 = (blockIdx.x & 63) * 16;
    for (int idx = tid; idx < 16 * D; idx += 256) {
        int r = idx / D, d = idx - r * D;
        Xi[r * XI_LD + d] = Hout[(size_t)(b * P + i0 + r) * 256 + colOff + d];
    }
    int i = tid & 15, q4 = tid >> 4;       // compute-phase mapping (coalesced)
    float rni = rn[b * P + i0 + i];
    int lane = tid & 63, w = tid >> 6;     // merge-phase mapping
    int g = lane >> 4, lane16 = lane & 15;
    int row = w * 4 + g;                   // row this 16-lane group merges
    int sh = lane & 48;
    unsigned long long listkey = 0ull;     // lane16-th entry of row's sorted top-16
    int nd4 = D >> 2;
    __syncthreads();
    for (int qt = 0; qt < 16; qt++) {
        int q0 = qt * 64;
        // ---- compute 16x64 sim tile (bit-identical accumulation order) ----
        {
            const float4* pq = (const float4*)(Hout + (size_t)(b * P + q0 + q4 * 4) * 256 + colOff);
            const float4* xi4 = (const float4*)(Xi + i * XI_LD);
            float a0 = 0.f, a1 = 0.f, a2 = 0.f, a3 = 0.f;
            for (int d4 = 0; d4 < nd4; d4++) {
                float4 xv = xi4[d4];
                float4 p0 = pq[d4];
                float4 p1 = pq[64 + d4];
                float4 p2 = pq[128 + d4];
                float4 p3 = pq[192 + d4];
                a0 += xv.x * p0.x; a0 += xv.y * p0.y; a0 += xv.z * p0.z; a0 += xv.w * p0.w;
                a1 += xv.x * p1.x; a1 += xv.y * p1.y; a1 += xv.z * p1.z; a1 += xv.w * p1.w;
                a2 += xv.x * p2.x; a2 += xv.y * p2.y; a2 += xv.z * p2.z; a2 += xv.w * p2.w;
                a3 += xv.x * p3.x; a3 += xv.y * p3.y; a3 += xv.z * p3.z; a3 += xv.w * p3.w;
            }
            int qb = q0 + q4 * 4;
            float v0 = a0 * rni * rn[b * P + qb + 0];
            float v1 = a1 * rni * rn[b * P + qb + 1];
            float v2 = a2 * rni * rn[b * P + qb + 2];
            float v3 = a3 * rni * rn[b * P + qb + 3];
            int ig = i0 + i;
            if (qb + 0 == ig) v0 = -1e9f;
            if (qb + 1 == ig) v1 = -1e9f;
            if (qb + 2 == ig) v2 = -1e9f;
            if (qb + 3 == ig) v3 = -1e9f;
            simtile[i * ST_LD + q4 * 4 + 0] = v0;
            simtile[i * ST_LD + q4 * 4 + 1] = v1;
            simtile[i * ST_LD + q4 * 4 + 2] = v2;
            simtile[i * ST_LD + q4 * 4 + 3] = v3;
        }
        __syncthreads();
        // ---- ballot-filter + blind-insert merge: 16 lanes per row ----
        {
            unsigned long long c0 = packkey(simtile[row * ST_LD + lane16     ], q0 + lane16);
            unsigned long long c1 = packkey(simtile[row * ST_LD + lane16 + 16], q0 + lane16 + 16);
            unsigned long long c2 = packkey(simtile[row * ST_LD + lane16 + 32], q0 + lane16 + 32);
            unsigned long long c3 = packkey(simtile[row * ST_LD + lane16 + 48], q0 + lane16 + 48);
            unsigned long long lmin = __shfl(listkey, 15, 16);
            unsigned long long b0 = __ballot(c0 > lmin);
            unsigned long long b1 = __ballot(c1 > lmin);
            unsigned long long b2 = __ballot(c2 > lmin);
            unsigned long long b3 = __ballot(c3 > lmin);
            unsigned long long gm = ((b0 >> sh) & 0xFFFFull)
                                  | (((b1 >> sh) & 0xFFFFull) << 16)
                                  | (((b2 >> sh) & 0xFFFFull) << 32)
                                  | (((b3 >> sh) & 0xFFFFull) << 48);
            // stale (too-small) candidates self-discard (pos==16 -> no-op)
            while (gm) {
                int pb = __builtin_ctzll(gm);
                gm &= gm - 1;
                int slot = pb >> 4, src = pb & 15;
                unsigned long long sel = (slot & 2) ? ((slot & 1) ? c3 : c2)
                                                    : ((slot & 1) ? c1 : c0);
                unsigned long long mv = __shfl(sel, src, 16);
                unsigned long long bal = __ballot(listkey > mv);
                int pos = __popcll((bal >> sh) & 0xFFFFull);
                unsigned long long up = __shfl_up(listkey, 1, 16);
                if (lane16 == pos) listkey = mv;
                else if (lane16 > pos) listkey = up;
            }
        }
        __syncthreads();
    }
    nbr[((size_t)b * P + i0 + row) * KNN + lane16] = 1023 - (int)(listkey & 0xFFFFFFFFull);
}

// ---------------- UV projection: [16384, D] @ [D, 192] ----------------
__global__ void k_uv(const float* __restrict__ Hout, int colOff, int D,
                     const float* __restrict__ WUV, float* __restrict__ UV) {
    __shared__ float Xt[16 * 192];
    int tid = threadIdx.x;   // 192 threads
    int p0 = blockIdx.x * 16;
    for (int idx = tid; idx < 16 * D; idx += 192) {
        int r = idx / D, d = idx - r * D;
        Xt[r * 192 + d] = Hout[(p0 + r) * 256 + colOff + d];
    }
    __syncthreads();
    float acc[16];
    #pragma unroll
    for (int p = 0; p < 16; p++) acc[p] = 0.f;
    for (int k = 0; k < D; k++) {
        float w = WUV[k * 192 + tid];
        #pragma unroll
        for (int p = 0; p < 16; p++) acc[p] += Xt[p * 192 + k] * w;
    }
    #pragma unroll
    for (int p = 0; p < 16; p++) UV[(size_t)(p0 + p) * 192 + tid] = acc[p];
}

// ---------------- per-edge message kernel (wb in VGPRs, no inner barriers) --
__global__ void __launch_bounds__(256) k_edge(const float* __restrict__ UV, const int* __restrict__ nbr,
                                              const float* __restrict__ wb, const float* __restrict__ bbv,
                                              const float* __restrict__ cvec, int colOut,
                                              float* __restrict__ Hout) {
    __shared__ __align__(16) float m1s[4][96];   // wave-private message buffer
    __shared__ float cvs[96];
    __shared__ float bbs[64];
    int tid = threadIdx.x;
    int w = tid >> 6, lane = tid & 63;
    float wreg[96];                              // wb column `lane` in registers
    #pragma unroll
    for (int k = 0; k < 96; k++) wreg[k] = wb[k * 64 + lane];
    if (tid < 96) cvs[tid] = cvec[tid];
    if (tid < 64) bbs[tid] = bbv[tid];
    int ifl = blockIdx.x * 4 + w;
    int b = ifl >> 10, i = ifl & 1023;
    const float* Ui = UV + (size_t)ifl * 192;
    float ui0 = Ui[lane];
    float ui1 = (lane < 32) ? Ui[64 + lane] : 0.f;
    float vi0 = Ui[96 + lane];
    float vi1 = (lane < 32) ? Ui[160 + lane] : 0.f;
    float accA = 0.f;
    __syncthreads();
    float bbl = bbs[lane];
    float cv0 = cvs[lane];
    float cv1 = (lane < 32) ? cvs[64 + lane] : 0.f;
    const float4* m4 = (const float4*)m1s[w];
    for (int kk = 0; kk < KNN; kk++) {
        int j = nbr[ifl * KNN + kk];
        int jf = b * P + j;
        bool mut = __any((lane < KNN) ? (nbr[jf * KNN + lane] == i) : 0);
        const float* Uj = UV + (size_t)jf * 192;
        // forward message: center i, neighbor j   (wave-private -> no barrier)
        m1s[w][lane] = fmaxf(ui0 + Uj[96 + lane] + cv0, 0.f);
        if (lane < 32) m1s[w][64 + lane] = fmaxf(ui1 + Uj[160 + lane] + cv1, 0.f);
        float t = bbl;
        #pragma unroll
        for (int k4 = 0; k4 < 24; k4++) {
            float4 mv = m4[k4];
            t += mv.x * wreg[k4 * 4 + 0];
            t += mv.y * wreg[k4 * 4 + 1];
            t += mv.z * wreg[k4 * 4 + 2];
            t += mv.w * wreg[k4 * 4 + 3];
        }
        accA += fmaxf(t, 0.f);
        // reverse message: center j, neighbor i
        m1s[w][lane] = fmaxf(Uj[lane] + vi0 + cv0, 0.f);
        if (lane < 32) m1s[w][64 + lane] = fmaxf(Uj[64 + lane] + vi1 + cv1, 0.f);
        float t2 = bbl;
        #pragma unroll
        for (int k4 = 0; k4 < 24; k4++) {
            float4 mv = m4[k4];
            t2 += mv.x * wreg[k4 * 4 + 0];
            t2 += mv.y * wreg[k4 * 4 + 1];
            t2 += mv.z * wreg[k4 * 4 + 2];
            t2 += mv.w * wreg[k4 * 4 + 3];
        }
        if (!mut) atomicAdd(&Hout[(size_t)jf * 256 + colOut + lane], fmaxf(t2, 0.f));
    }
    atomicAdd(&Hout[(size_t)ifl * 256 + colOut + lane], accA);
}

// ---------------- global max pool (partial) ----------------
__global__ void k_pool(const float* __restrict__ Hout, float* __restrict__ part) {
    int tid = threadIdx.x;
    int b = blockIdx.x >> 4, pt = blockIdx.x & 15;
    float mv = -1e30f;
    for (int p = pt * 64; p < pt * 64 + 64; p++)
        mv = fmaxf(mv, Hout[(size_t)(b * P + p) * 256 + tid]);
    part[(b * 16 + pt) * 256 + tid] = mv;
}

// ---------------- final reduce + output MLP ----------------
__global__ void k_out(const float* __restrict__ part,
                      const float* __restrict__ w1, const float* __restrict__ b1,
                      const float* __restrict__ w2, const float* __restrict__ b2,
                      const float* __restrict__ w3, const float* __restrict__ b3,
                      float* __restrict__ out) {
    __shared__ float pooled[256];
    __shared__ float r1[128];
    __shared__ float r2[32];
    int tid = threadIdx.x, b = blockIdx.x;
    float mv = -1e30f;
    for (int t = 0; t < 16; t++) mv = fmaxf(mv, part[(b * 16 + t) * 256 + tid]);
    pooled[tid] = mv;
    __syncthreads();
    if (tid < 128) {
        float a = b1[tid];
        for (int k = 0; k < 256; k++) a += pooled[k] * w1[k * 128 + tid];
        r1[tid] = fmaxf(a, 0.f);
    }
    __syncthreads();
    if (tid < 32) {
        float a = b2[tid];
        for (int k = 0; k < 128; k++) a += r1[k] * w2[k * 32 + tid];
        r2[tid] = fmaxf(a, 0.f);
    }
    __syncthreads();
    if (tid == 0) {
        float a = b3[0];
        for (int k = 0; k < 32; k++) a += r2[k] * w3[k];
        out[b] = a;
    }
}

extern "C" void kernel_launch(void* const* d_in, const int* in_sizes, int n_in,
                              void* d_out, int out_size, void* d_ws, size_t ws_size,
                              hipStream_t stream) {
    const float* x  = (const float*)d_in[0];
    const float* dn = (const float*)d_in[1];
    float* out = (float*)d_out;
    float* Hout = out + 16;           // [16384][256] feature/output buffer
    float* ws = (float*)d_ws;
    float* UV   = ws + WS_UV;
    float* rn   = ws + WS_RN;
    int*   nbr  = (int*)(ws + WS_NBR);
    float* WUV  = ws + WS_WUV;
    float* cvec = ws + WS_CVEC;
    float* part = ws + WS_PART;

    hipMemsetAsync(d_out, 0, (size_t)out_size * sizeof(float), stream);

    k_input<<<2048, 128, 0, stream>>>(x, dn,
        (const float*)d_in[2], (const float*)d_in[3],
        (const float*)d_in[4], (const float*)d_in[5],
        (const float*)d_in[6], (const float*)d_in[7], Hout);

    const int convOff[3] = {192, 128, 64};   // input column offset
    const int convD[3]   = {64, 128, 192};   // input feature width
    const int convOut[3] = {128, 64, 0};     // output column offset
    for (int c = 0; c < 3; c++) {
        int pb = 8 + c * 8;
        const float* wa  = (const float*)d_in[pb + 0];
        const float* ba  = (const float*)d_in[pb + 1];
        const float* g   = (const float*)d_in[pb + 2];
        const float* bB  = (const float*)d_in[pb + 3];
        const float* m   = (const float*)d_in[pb + 4];
        const float* v   = (const float*)d_in[pb + 5];
        const float* wb  = (const float*)d_in[pb + 6];
        const float* bbv = (const float*)d_in[pb + 7];
        int D = convD[c], off = convOff[c], co = convOut[c];
        k_prep<<<(D * 192 + 255) / 256, 256, 0, stream>>>(wa, ba, g, bB, m, v, D, WUV, cvec);
        k_rn<<<64, 256, 0, stream>>>(Hout, off, D, rn);
        k_knn<<<1024, 256, 0, stream>>>(Hout, off, D, rn, nbr);
        k_uv<<<1024, 192, 0, stream>>>(Hout, off, D, WUV, UV);
        k_edge<<<4096, 256, 0, stream>>>(UV, nbr, wb, bbv, cvec, co, Hout);
    }

    k_pool<<<256, 256, 0, stream>>>(Hout, part);
    k_out<<<16, 256, 0, stream>>>(part,
        (const float*)d_in[32], (const float*)d_in[33],
        (const float*)d_in[34], (const float*)d_in[35],
        (const float*)d_in[36], (const float*)d_in[37], out);
}